// Round 3
// baseline (260.428 us; speedup 1.0000x reference)
//
#include <hip/hip_runtime.h>

#define NB 2048
#define NM 128
#define ND 5
#define NFA 62
#define NFB 6
#define NFAN 68
#define NC 128
#define KP 96       // W row in shorts: 68 payload + 28 zero pad (3 x K=32 MFMA slices)
                    // global/L1-resident; max read index = 128*96-1 (in-bounds by construction)

typedef __bf16 bf16x8 __attribute__((ext_vector_type(8)));
typedef float floatx4 __attribute__((ext_vector_type(4)));

__device__ __forceinline__ unsigned short f2bf(float x) {
    unsigned u = __builtin_bit_cast(unsigned, x);
    u += 0x7FFFu + ((u >> 16) & 1u);   // RNE
    return (unsigned short)(u >> 16);
}

// Pack W_self (68x128 fp32, k-major) -> wsb as bf16 [c][96] (c-major, K zero-padded).
// 128*96*2 = 24576 B workspace.
__global__ __launch_bounds__(256) void prep_w(const float* __restrict__ W_self,
                                              unsigned short* __restrict__ wsb) {
    const int i = blockIdx.x * 256 + threadIdx.x;   // i < 128*96 = 12288 (48 blocks exact)
    const int c = i / KP;
    const int f = i - c * KP;
    unsigned short v = 0;
    if (f < NFAN) v = f2bf(W_self[f * NC + c]);
    wsb[i] = v;
}

// async global->LDS; LDS dest = wave-uniform base, HW adds lane*size
__device__ __forceinline__ void glds16(const void* g, void* l) {
    __builtin_amdgcn_global_load_lds(
        (const __attribute__((address_space(1))) unsigned int*)g,
        (__attribute__((address_space(3))) unsigned int*)l,
        16, 0, 0);
}
__device__ __forceinline__ void glds4(const void* g, void* l) {
    __builtin_amdgcn_global_load_lds(
        (const __attribute__((address_space(1))) unsigned int*)g,
        (__attribute__((address_space(3))) unsigned int*)l,
        4, 0, 0);
}

__device__ __forceinline__ bf16x8 load8(const float* p) {
    float2 v0 = *(const float2*)(p);
    float2 v1 = *(const float2*)(p + 2);
    float2 v2 = *(const float2*)(p + 4);
    float2 v3 = *(const float2*)(p + 6);
    bf16x8 r;
    r[0] = (__bf16)v0.x; r[1] = (__bf16)v0.y; r[2] = (__bf16)v1.x; r[3] = (__bf16)v1.y;
    r[4] = (__bf16)v2.x; r[5] = (__bf16)v2.y; r[6] = (__bf16)v3.x; r[7] = (__bf16)v3.y;
    return r;
}

// floats p[0..5] (atoms features 56..61) + bond sums bs[0],bs[1] (features 62,63)
__device__ __forceinline__ bf16x8 load6bs(const float* p, const float* bs) {
    float2 v0 = *(const float2*)(p);
    float2 v1 = *(const float2*)(p + 2);
    float2 v2 = *(const float2*)(p + 4);
    float2 b01 = *(const float2*)(bs);
    bf16x8 r;
    r[0] = (__bf16)v0.x; r[1] = (__bf16)v0.y; r[2] = (__bf16)v1.x; r[3] = (__bf16)v1.y;
    r[4] = (__bf16)v2.x; r[5] = (__bf16)v2.y; r[6] = (__bf16)b01.x; r[7] = (__bf16)b01.y;
    return r;
}

__global__ __launch_bounds__(256) void tga_wave(
    const float* __restrict__ atoms,
    const float* __restrict__ bonds,
    const int*   __restrict__ edges,
    const float* __restrict__ W_inner,
    const float* __restrict__ b_inner,
    const float* __restrict__ b_self,
    const unsigned short* __restrict__ wsb,
    float* __restrict__ out)
{
    // All LDS is wave-private regions; NO __syncthreads anywhere.
    // 31744 + 4096 + 1024 = 36864 B -> 4 blocks/CU (vs 2 before).
    __shared__ __align__(16) float s_atoms[NM * NFA];   // [row][62] fp32, wave w owns rows w*32..w*32+31
    __shared__ __align__(16) float s_bsf[4][32][8];     // per row: [bs2..bs5, bs0,bs1, -, -]
    __shared__ float s_sf[4][64];                       // sparse-path summed-atom features

    const int tid  = threadIdx.x;
    const int w    = tid >> 6;
    const int lane = tid & 63;
    const int b    = blockIdx.x;
    const int m0   = w * 32;      // this wave owns rows m0..m0+31

    const float* atoms_b = atoms + (size_t)b * (NM * NFA);
    const float* bonds_b = bonds + (size_t)b * (NM * ND * NFB);
    const int*   edges_b = edges + (size_t)b * (NM * ND);
    float*       out_b   = out   + (size_t)b * (NM * NC);

    // ---- async stage THIS WAVE's 32 atom rows (7936 B) into its LDS region ----
    {
        const char* ga = (const char*)atoms_b + w * 7936;
        char* la = (char*)s_atoms + w * 7936;
        #pragma unroll
        for (int i = 0; i < 7; ++i)
            glds16(ga + i * 1024 + lane * 16, la + i * 1024);
        #pragma unroll
        for (int j = 0; j < 3; ++j)
            glds4(ga + 7168 + j * 256 + lane * 4, la + 7168 + j * 256);
    }

    // ---- edges + degree (lanes 0..31, one row each) — overlaps staging ----
    int E0 = -1, E1 = -1, E2 = -1, E3 = -1, E4 = -1, deg = ND;
    if (lane < 32) {
        const int* e = edges_b + (m0 + lane) * ND;
        E0 = e[0]; E1 = e[1]; E2 = e[2]; E3 = e[3]; E4 = e[4];
        deg = (E0 >= 0) + (E1 >= 0) + (E2 >= 0) + (E3 >= 0) + (E4 >= 0);
    }
    unsigned long long smask = __ballot((lane < 32) && (deg < ND));

    // ---- bond sums from global: 2 lanes per row, combine via shfl_xor ----
    {
        const int rb = lane >> 1, half = lane & 1;
        const float* bp = bonds_b + (m0 + rb) * (ND * NFB);
        float sb[NFB] = {0.f, 0.f, 0.f, 0.f, 0.f, 0.f};
        if (half == 0) {
            #pragma unroll
            for (int p = 0; p < 8; ++p) {
                float2 v = *(const float2*)&bp[2 * p];
                sb[(2 * p) % NFB]     += v.x;
                sb[(2 * p + 1) % NFB] += v.y;
            }
        } else {
            #pragma unroll
            for (int p = 8; p < 15; ++p) {
                float2 v = *(const float2*)&bp[2 * p];
                sb[(2 * p) % NFB]     += v.x;
                sb[(2 * p + 1) % NFB] += v.y;
            }
        }
        #pragma unroll
        for (int j = 0; j < NFB; ++j) sb[j] += __shfl_xor(sb[j], 1);
        if (half == 0) {
            *(float4*)&s_bsf[w][rb][0] = make_float4(sb[2], sb[3], sb[4], sb[5]);
            *(float2*)&s_bsf[w][rb][4] = make_float2(sb[0], sb[1]);
        }
    }
    __builtin_amdgcn_wave_barrier();

    // Drain this wave's global_load_lds (vmcnt) before reading s_atoms.
    asm volatile("s_waitcnt vmcnt(0)" ::: "memory");

    // ---- build A-fragments (vxi) from LDS atoms, MFMA A-layout ----
    const int col = lane & 15, quad = lane >> 4;
    const int lr0 = col, lr1 = 16 + col;          // wave-local rows
    const float* p0 = s_atoms + (m0 + lr0) * NFA;
    const float* p1 = s_atoms + (m0 + lr1) * NFA;

    bf16x8 a00 = load8(p0 + quad * 8);
    bf16x8 a10 = load8(p1 + quad * 8);
    bf16x8 a01, a11;
    if (quad < 3) {
        a01 = load8(p0 + 32 + quad * 8);
        a11 = load8(p1 + 32 + quad * 8);
    } else {
        a01 = load6bs(p0 + 56, &s_bsf[w][lr0][4]);
        a11 = load6bs(p1 + 56, &s_bsf[w][lr1][4]);
    }
    bf16x8 a02, a12;
    #pragma unroll
    for (int j = 0; j < 8; ++j) { a02[j] = (__bf16)0.f; a12[j] = (__bf16)0.f; }
    if (quad == 0) {
        float4 q0 = *(const float4*)&s_bsf[w][lr0][0];
        float4 q1 = *(const float4*)&s_bsf[w][lr1][0];
        a02[0] = (__bf16)q0.x; a02[1] = (__bf16)q0.y; a02[2] = (__bf16)q0.z; a02[3] = (__bf16)q0.w;
        a12[0] = (__bf16)q1.x; a12[1] = (__bf16)q1.y; a12[2] = (__bf16)q1.z; a12[3] = (__bf16)q1.w;
    }

    // ---- MFMA: stream W fragments from L1-resident wsb (shared by all blocks on CU) ----
    floatx4 acc[16];
    #pragma unroll
    for (int t = 0; t < 16; ++t) { floatx4 z; z[0] = z[1] = z[2] = z[3] = 0.f; acc[t] = z; }

    const unsigned short* wbase = wsb + (size_t)col * KP + quad * 8;
    #pragma unroll
    for (int ct = 0; ct < 8; ++ct) {
        bf16x8 wf0 = *(const bf16x8*)(wbase + ct * 16 * KP);
        bf16x8 wf1 = *(const bf16x8*)(wbase + ct * 16 * KP + 32);
        bf16x8 wf2 = *(const bf16x8*)(wbase + ct * 16 * KP + 64);
        acc[ct]     = __builtin_amdgcn_mfma_f32_16x16x32_bf16(a00, wf0, acc[ct],     0, 0, 0);
        acc[8 + ct] = __builtin_amdgcn_mfma_f32_16x16x32_bf16(a10, wf0, acc[8 + ct], 0, 0, 0);
        acc[ct]     = __builtin_amdgcn_mfma_f32_16x16x32_bf16(a01, wf1, acc[ct],     0, 0, 0);
        acc[8 + ct] = __builtin_amdgcn_mfma_f32_16x16x32_bf16(a11, wf1, acc[8 + ct], 0, 0, 0);
        acc[ct]     = __builtin_amdgcn_mfma_f32_16x16x32_bf16(a02, wf2, acc[ct],     0, 0, 0);
        acc[8 + ct] = __builtin_amdgcn_mfma_f32_16x16x32_bf16(a12, wf2, acc[8 + ct], 0, 0, 0);
    }

    // ---- epilogue: bias + relu, coalesced dword stores (full 64B lines) ----
    #pragma unroll
    for (int ct = 0; ct < 8; ++ct) {
        const float bias = b_self[ct * 16 + col];
        #pragma unroll
        for (int rr = 0; rr < 4; ++rr) {
            const int row0 = m0 + quad * 4 + rr;
            out_b[row0 * NC + ct * 16 + col]        = fmaxf(acc[ct][rr]     + bias, 0.f);
            out_b[(row0 + 16) * NC + ct * 16 + col] = fmaxf(acc[8 + ct][rr] + bias, 0.f);
        }
    }

    // ---- sparse path: rows with deg<5 (~1.2/wave); neighbor gathers from global
    //      (cross-wave LDS rows aren't guaranteed staged without a block barrier) ----
    while (smask) {
        const int ml = __ffsll(smask) - 1;
        smask &= smask - 1;
        const int m  = m0 + ml;
        const int d  = __shfl(deg, ml);
        const int e0 = __shfl(E0, ml), e1 = __shfl(E1, ml), e2 = __shfl(E2, ml),
                  e3 = __shfl(E3, ml), e4 = __shfl(E4, ml);

        if (lane < NFA) {   // coalesced 248B gathers per neighbor (L1/L2-hot)
            float sv = 0.f;
            if (e0 >= 0) sv += atoms_b[e0 * NFA + lane];
            if (e1 >= 0) sv += atoms_b[e1 * NFA + lane];
            if (e2 >= 0) sv += atoms_b[e2 * NFA + lane];
            if (e3 >= 0) sv += atoms_b[e3 * NFA + lane];
            if (e4 >= 0) sv += atoms_b[e4 * NFA + lane];
            s_sf[w][lane] = sv;
        }
        __builtin_amdgcn_wave_barrier();

        const int c0 = 2 * lane;
        float2 bi = *(const float2*)&b_inner[d * NC + c0];
        float acc0 = bi.x, acc1 = bi.y;
        const float* Wd = W_inner + (size_t)d * (NFAN * NC);
        #pragma unroll
        for (int f = 0; f < NFA; ++f) {
            const float sfv = s_sf[w][f];
            float2 wv = *(const float2*)&Wd[f * NC + c0];
            acc0 += sfv * wv.x; acc1 += sfv * wv.y;
        }
        {
            const float* bb = &s_bsf[w][ml][0];
            const float fv[6] = {bb[4], bb[5], bb[0], bb[1], bb[2], bb[3]}; // bs0..bs5
            #pragma unroll
            for (int j = 0; j < NFB; ++j) {
                float2 wv = *(const float2*)&Wd[(NFA + j) * NC + c0];
                acc0 += fv[j] * wv.x; acc1 += fv[j] * wv.y;
            }
        }
        float2 cur = *(float2*)&out_b[m * NC + c0];
        cur.x += fmaxf(acc0, 0.f);
        cur.y += fmaxf(acc1, 0.f);
        *(float2*)&out_b[m * NC + c0] = cur;
        __builtin_amdgcn_wave_barrier();
    }
}

extern "C" void kernel_launch(void* const* d_in, const int* in_sizes, int n_in,
                              void* d_out, int out_size, void* d_ws, size_t ws_size,
                              hipStream_t stream) {
    const float* atoms   = (const float*)d_in[0];
    const float* bonds   = (const float*)d_in[1];
    const int*   edges   = (const int*)d_in[2];
    const float* W_inner = (const float*)d_in[3];
    const float* b_inner = (const float*)d_in[4];
    const float* W_self  = (const float*)d_in[5];
    const float* b_self  = (const float*)d_in[6];
    float* out = (float*)d_out;
    unsigned short* wsb = (unsigned short*)d_ws;   // 128*96*2 = 24576 B

    prep_w<<<(NC * KP) / 256, 256, 0, stream>>>(W_self, wsb);
    tga_wave<<<NB, 256, 0, stream>>>(atoms, bonds, edges, W_inner, b_inner,
                                     b_self, wsb, out);
}

// Round 4
// 257.278 us; speedup vs baseline: 1.0122x; 1.0122x over previous
//
#include <hip/hip_runtime.h>

#define NB 2048
#define NM 128
#define ND 5
#define NFA 62
#define NFB 6
#define NFAN 68
#define NC 128
#define KTOT 96     // padded K: 3 slices x 32 (68 payload + 28 zeros)

typedef __bf16 bf16x8 __attribute__((ext_vector_type(8)));
typedef float floatx4 __attribute__((ext_vector_type(4)));

__device__ __forceinline__ unsigned short f2bf(float x) {
    unsigned u = __builtin_bit_cast(unsigned, x);
    u += 0x7FFFu + ((u >> 16) & 1u);   // RNE
    return (unsigned short)(u >> 16);
}

// Pack W_self (68x128 fp32, k-major) -> wsb in MFMA FRAGMENT ORDER:
//   fragment index = (ct*3 + slice)*64 + lane   (lane = quad*16 + col), 16 B each.
//   Element e of fragment holds W[k][c], k = slice*32 + quad*8 + e, c = ct*16 + col.
// A wave's ds_read_b128 for (ct,slice) is then base + lane*16 -> linear, conflict-free,
// and matches global_load_lds's linear LDS write order (both-sides-linear, no swizzle).
__global__ __launch_bounds__(256) void prep_w(const float* __restrict__ W_self,
                                              unsigned short* __restrict__ wsb) {
    const int i = blockIdx.x * 256 + threadIdx.x;   // i < 128*96 = 12288 (48 blocks exact)
    const int e     = i & 7;
    const int chunk = i >> 3;          // 16B fragment id, 0..1535
    const int lane  = chunk & 63;
    const int cs    = chunk >> 6;      // ct*3 + slice, 0..23
    const int ct    = cs / 3;
    const int slice = cs - 3 * ct;
    const int quad  = lane >> 4;
    const int col   = lane & 15;
    const int k     = slice * 32 + quad * 8 + e;
    const int c     = ct * 16 + col;
    unsigned short v = 0;
    if (k < NFAN) v = f2bf(W_self[k * NC + c]);
    wsb[i] = v;
}

// async global->LDS; LDS dest = wave-uniform base, HW adds lane*size
__device__ __forceinline__ void glds16(const void* g, void* l) {
    __builtin_amdgcn_global_load_lds(
        (const __attribute__((address_space(1))) unsigned int*)g,
        (__attribute__((address_space(3))) unsigned int*)l,
        16, 0, 0);
}

__device__ __forceinline__ bf16x8 load8(const float* p) {
    float2 v0 = *(const float2*)(p);
    float2 v1 = *(const float2*)(p + 2);
    float2 v2 = *(const float2*)(p + 4);
    float2 v3 = *(const float2*)(p + 6);
    bf16x8 r;
    r[0] = (__bf16)v0.x; r[1] = (__bf16)v0.y; r[2] = (__bf16)v1.x; r[3] = (__bf16)v1.y;
    r[4] = (__bf16)v2.x; r[5] = (__bf16)v2.y; r[6] = (__bf16)v3.x; r[7] = (__bf16)v3.y;
    return r;
}

// floats p[0..5] (atoms features 56..61) + bond sums bs[0],bs[1] (features 62,63)
__device__ __forceinline__ bf16x8 load6bs(const float* p, const float* bs) {
    float2 v0 = *(const float2*)(p);
    float2 v1 = *(const float2*)(p + 2);
    float2 v2 = *(const float2*)(p + 4);
    float2 b01 = *(const float2*)(bs);
    bf16x8 r;
    r[0] = (__bf16)v0.x; r[1] = (__bf16)v0.y; r[2] = (__bf16)v1.x; r[3] = (__bf16)v1.y;
    r[4] = (__bf16)v2.x; r[5] = (__bf16)v2.y; r[6] = (__bf16)b01.x; r[7] = (__bf16)b01.y;
    return r;
}

__global__ __launch_bounds__(256) void tga_wave(
    const float* __restrict__ atoms,
    const float* __restrict__ bonds,
    const int*   __restrict__ edges,
    const float* __restrict__ W_inner,
    const float* __restrict__ b_inner,
    const float* __restrict__ b_self,
    const unsigned short* __restrict__ wsb,
    float* __restrict__ out)
{
    // 24576 + 4096 + 1024 = 29696 B static LDS.
    __shared__ __align__(16) unsigned short s_w[NC * KTOT];  // fragment-ordered W, 24.6 KB
    __shared__ __align__(16) float s_bsf[4][32][8];          // per row: [bs2..bs5, bs0,bs1, -, -]
    __shared__ float s_sf[4][64];                            // sparse-path summed-atom features

    const int tid  = threadIdx.x;
    const int w    = tid >> 6;
    const int lane = tid & 63;
    const int b    = blockIdx.x;
    const int m0   = w * 32;      // this wave owns rows m0..m0+31

    const float* atoms_b = atoms + (size_t)b * (NM * NFA);
    const float* bonds_b = bonds + (size_t)b * (NM * ND * NFB);
    const int*   edges_b = edges + (size_t)b * (NM * ND);
    float*       out_b   = out   + (size_t)b * (NM * NC);

    // ---- async stage W (24 x 1 KiB chunks) into LDS, waves round-robin ----
    {
        const char* gw = (const char*)wsb;
        char* lw = (char*)s_w;
        for (int ch = w; ch < 24; ch += 4)          // wave-uniform guard
            glds16(gw + ch * 1024 + lane * 16, lw + ch * 1024);
    }

    // ---- edges + degree (lanes 0..31, one row each) — overlaps staging ----
    int E0 = -1, E1 = -1, E2 = -1, E3 = -1, E4 = -1, deg = ND;
    if (lane < 32) {
        const int* e = edges_b + (m0 + lane) * ND;
        E0 = e[0]; E1 = e[1]; E2 = e[2]; E3 = e[3]; E4 = e[4];
        deg = (E0 >= 0) + (E1 >= 0) + (E2 >= 0) + (E3 >= 0) + (E4 >= 0);
    }
    unsigned long long smask = __ballot((lane < 32) && (deg < ND));

    // ---- bond sums from global: 2 lanes per row, combine via shfl_xor ----
    {
        const int rb = lane >> 1, half = lane & 1;
        const float* bp = bonds_b + (m0 + rb) * (ND * NFB);
        float sb[NFB] = {0.f, 0.f, 0.f, 0.f, 0.f, 0.f};
        if (half == 0) {
            #pragma unroll
            for (int p = 0; p < 8; ++p) {
                float2 v = *(const float2*)&bp[2 * p];
                sb[(2 * p) % NFB]     += v.x;
                sb[(2 * p + 1) % NFB] += v.y;
            }
        } else {
            #pragma unroll
            for (int p = 8; p < 15; ++p) {
                float2 v = *(const float2*)&bp[2 * p];
                sb[(2 * p) % NFB]     += v.x;
                sb[(2 * p + 1) % NFB] += v.y;
            }
        }
        #pragma unroll
        for (int j = 0; j < NFB; ++j) sb[j] += __shfl_xor(sb[j], 1);
        if (half == 0) {
            *(float4*)&s_bsf[w][rb][0] = make_float4(sb[2], sb[3], sb[4], sb[5]);
            *(float2*)&s_bsf[w][rb][4] = make_float2(sb[0], sb[1]);
        }
    }

    // ---- build A-fragments (vxi) from GLOBAL atoms (L1-served), MFMA A-layout ----
    const int col = lane & 15, quad = lane >> 4;
    const int lr0 = col, lr1 = 16 + col;          // wave-local rows
    const float* p0 = atoms_b + (m0 + lr0) * NFA;
    const float* p1 = atoms_b + (m0 + lr1) * NFA;

    bf16x8 a00 = load8(p0 + quad * 8);
    bf16x8 a10 = load8(p1 + quad * 8);

    __syncthreads();   // drains glds (vmcnt) + s_bsf writes; s_w and s_bsf valid below

    bf16x8 a01, a11;
    if (quad < 3) {
        a01 = load8(p0 + 32 + quad * 8);
        a11 = load8(p1 + 32 + quad * 8);
    } else {
        a01 = load6bs(p0 + 56, &s_bsf[w][lr0][4]);
        a11 = load6bs(p1 + 56, &s_bsf[w][lr1][4]);
    }
    bf16x8 a02, a12;
    #pragma unroll
    for (int j = 0; j < 8; ++j) { a02[j] = (__bf16)0.f; a12[j] = (__bf16)0.f; }
    if (quad == 0) {
        float4 q0 = *(const float4*)&s_bsf[w][lr0][0];
        float4 q1 = *(const float4*)&s_bsf[w][lr1][0];
        a02[0] = (__bf16)q0.x; a02[1] = (__bf16)q0.y; a02[2] = (__bf16)q0.z; a02[3] = (__bf16)q0.w;
        a12[0] = (__bf16)q1.x; a12[1] = (__bf16)q1.y; a12[2] = (__bf16)q1.z; a12[3] = (__bf16)q1.w;
    }

    // ---- MFMA: W fragments from LDS, linear base + lane*16 (conflict-free) ----
    floatx4 acc[16];
    #pragma unroll
    for (int t = 0; t < 16; ++t) { floatx4 z; z[0] = z[1] = z[2] = z[3] = 0.f; acc[t] = z; }

    const unsigned short* wl = s_w + lane * 8;   // 8 shorts = 16 B per fragment
    #pragma unroll
    for (int ct = 0; ct < 8; ++ct) {
        bf16x8 wf0 = *(const bf16x8*)(wl + (ct * 3 + 0) * 512);  // k  0..31, col ct*16+col
        bf16x8 wf1 = *(const bf16x8*)(wl + (ct * 3 + 1) * 512);  // k 32..63
        bf16x8 wf2 = *(const bf16x8*)(wl + (ct * 3 + 2) * 512);  // k 64..95 (rows>=68 zero)
        acc[ct]     = __builtin_amdgcn_mfma_f32_16x16x32_bf16(a00, wf0, acc[ct],     0, 0, 0);
        acc[8 + ct] = __builtin_amdgcn_mfma_f32_16x16x32_bf16(a10, wf0, acc[8 + ct], 0, 0, 0);
        acc[ct]     = __builtin_amdgcn_mfma_f32_16x16x32_bf16(a01, wf1, acc[ct],     0, 0, 0);
        acc[8 + ct] = __builtin_amdgcn_mfma_f32_16x16x32_bf16(a11, wf1, acc[8 + ct], 0, 0, 0);
        acc[ct]     = __builtin_amdgcn_mfma_f32_16x16x32_bf16(a02, wf2, acc[ct],     0, 0, 0);
        acc[8 + ct] = __builtin_amdgcn_mfma_f32_16x16x32_bf16(a12, wf2, acc[8 + ct], 0, 0, 0);
    }

    // ---- epilogue: bias + relu, coalesced dword stores (full 64B lines) ----
    #pragma unroll
    for (int ct = 0; ct < 8; ++ct) {
        const float bias = b_self[ct * 16 + col];
        #pragma unroll
        for (int rr = 0; rr < 4; ++rr) {
            const int row0 = m0 + quad * 4 + rr;
            out_b[row0 * NC + ct * 16 + col]        = fmaxf(acc[ct][rr]     + bias, 0.f);
            out_b[(row0 + 16) * NC + ct * 16 + col] = fmaxf(acc[8 + ct][rr] + bias, 0.f);
        }
    }

    // ---- sparse path: rows with deg<5 (~1.2/wave); neighbor gathers from global ----
    while (smask) {
        const int ml = __ffsll(smask) - 1;
        smask &= smask - 1;
        const int m  = m0 + ml;
        const int d  = __shfl(deg, ml);
        const int e0 = __shfl(E0, ml), e1 = __shfl(E1, ml), e2 = __shfl(E2, ml),
                  e3 = __shfl(E3, ml), e4 = __shfl(E4, ml);

        if (lane < NFA) {   // coalesced 248B gathers per neighbor (L1/L2-hot)
            float sv = 0.f;
            if (e0 >= 0) sv += atoms_b[e0 * NFA + lane];
            if (e1 >= 0) sv += atoms_b[e1 * NFA + lane];
            if (e2 >= 0) sv += atoms_b[e2 * NFA + lane];
            if (e3 >= 0) sv += atoms_b[e3 * NFA + lane];
            if (e4 >= 0) sv += atoms_b[e4 * NFA + lane];
            s_sf[w][lane] = sv;
        }
        __builtin_amdgcn_wave_barrier();

        const int c0 = 2 * lane;
        float2 bi = *(const float2*)&b_inner[d * NC + c0];
        float acc0 = bi.x, acc1 = bi.y;
        const float* Wd = W_inner + (size_t)d * (NFAN * NC);
        #pragma unroll
        for (int f = 0; f < NFA; ++f) {
            const float sfv = s_sf[w][f];
            float2 wv = *(const float2*)&Wd[f * NC + c0];
            acc0 += sfv * wv.x; acc1 += sfv * wv.y;
        }
        {
            const float* bb = &s_bsf[w][ml][0];
            const float fv[6] = {bb[4], bb[5], bb[0], bb[1], bb[2], bb[3]}; // bs0..bs5
            #pragma unroll
            for (int j = 0; j < NFB; ++j) {
                float2 wv = *(const float2*)&Wd[(NFA + j) * NC + c0];
                acc0 += fv[j] * wv.x; acc1 += fv[j] * wv.y;
            }
        }
        float2 cur = *(float2*)&out_b[m * NC + c0];
        cur.x += fmaxf(acc0, 0.f);
        cur.y += fmaxf(acc1, 0.f);
        *(float2*)&out_b[m * NC + c0] = cur;
        __builtin_amdgcn_wave_barrier();
    }
}

extern "C" void kernel_launch(void* const* d_in, const int* in_sizes, int n_in,
                              void* d_out, int out_size, void* d_ws, size_t ws_size,
                              hipStream_t stream) {
    const float* atoms   = (const float*)d_in[0];
    const float* bonds   = (const float*)d_in[1];
    const int*   edges   = (const int*)d_in[2];
    const float* W_inner = (const float*)d_in[3];
    const float* b_inner = (const float*)d_in[4];
    const float* W_self  = (const float*)d_in[5];
    const float* b_self  = (const float*)d_in[6];
    float* out = (float*)d_out;
    unsigned short* wsb = (unsigned short*)d_ws;   // 128*96*2 = 24576 B

    prep_w<<<(NC * KTOT) / 256, 256, 0, stream>>>(W_self, wsb);
    tga_wave<<<NB, 256, 0, stream>>>(atoms, bonds, edges, W_inner, b_inner,
                                     b_self, wsb, out);
}

// Round 6
// 246.353 us; speedup vs baseline: 1.0571x; 1.0443x over previous
//
#include <hip/hip_runtime.h>

#define NB 2048
#define NM 128
#define ND 5
#define NFA 62
#define NFB 6
#define NFAN 68
#define NC 128
#define KTOT 96     // padded K: 3 slices x 32 (68 payload + 28 zeros)

typedef __bf16 bf16x8 __attribute__((ext_vector_type(8)));
typedef float floatx4 __attribute__((ext_vector_type(4)));

__device__ __forceinline__ unsigned short f2bf(float x) {
    unsigned u = __builtin_bit_cast(unsigned, x);
    u += 0x7FFFu + ((u >> 16) & 1u);   // RNE
    return (unsigned short)(u >> 16);
}

// Pack W_self (68x128 fp32, k-major) -> wsb in MFMA FRAGMENT ORDER:
//   fragment index = (ct*3 + slice)*64 + lane   (lane = quad*16 + col), 16 B each.
//   Element e of fragment holds W[k][c], k = slice*32 + quad*8 + e, c = ct*16 + col.
// A wave's ds_read_b128 for (ct,slice) is then base + lane*16 -> linear, conflict-free,
// and matches global_load_lds's linear LDS write order (both-sides-linear, no swizzle).
__global__ __launch_bounds__(256) void prep_w(const float* __restrict__ W_self,
                                              unsigned short* __restrict__ wsb) {
    const int i = blockIdx.x * 256 + threadIdx.x;   // i < 128*96 = 12288 (48 blocks exact)
    const int e     = i & 7;
    const int chunk = i >> 3;          // 16B fragment id, 0..1535
    const int lane  = chunk & 63;
    const int cs    = chunk >> 6;      // ct*3 + slice, 0..23
    const int ct    = cs / 3;
    const int slice = cs - 3 * ct;
    const int quad  = lane >> 4;
    const int col   = lane & 15;
    const int k     = slice * 32 + quad * 8 + e;
    const int c     = ct * 16 + col;
    unsigned short v = 0;
    if (k < NFAN) v = f2bf(W_self[k * NC + c]);
    wsb[i] = v;
}

// async global->LDS; LDS dest = wave-uniform base, HW adds lane*size
__device__ __forceinline__ void glds16(const void* g, void* l) {
    __builtin_amdgcn_global_load_lds(
        (const __attribute__((address_space(1))) unsigned int*)g,
        (__attribute__((address_space(3))) unsigned int*)l,
        16, 0, 0);
}

__device__ __forceinline__ bf16x8 load8(const float* p) {
    float2 v0 = *(const float2*)(p);
    float2 v1 = *(const float2*)(p + 2);
    float2 v2 = *(const float2*)(p + 4);
    float2 v3 = *(const float2*)(p + 6);
    bf16x8 r;
    r[0] = (__bf16)v0.x; r[1] = (__bf16)v0.y; r[2] = (__bf16)v1.x; r[3] = (__bf16)v1.y;
    r[4] = (__bf16)v2.x; r[5] = (__bf16)v2.y; r[6] = (__bf16)v3.x; r[7] = (__bf16)v3.y;
    return r;
}

// floats p[0..5] (atoms features 56..61) + bond sums bs[0],bs[1] (features 62,63)
__device__ __forceinline__ bf16x8 load6bs(const float* p, const float* bs) {
    float2 v0 = *(const float2*)(p);
    float2 v1 = *(const float2*)(p + 2);
    float2 v2 = *(const float2*)(p + 4);
    float2 b01 = *(const float2*)(bs);
    bf16x8 r;
    r[0] = (__bf16)v0.x; r[1] = (__bf16)v0.y; r[2] = (__bf16)v1.x; r[3] = (__bf16)v1.y;
    r[4] = (__bf16)v2.x; r[5] = (__bf16)v2.y; r[6] = (__bf16)b01.x; r[7] = (__bf16)b01.y;
    return r;
}

__global__ __launch_bounds__(256) void tga_wave(
    const float* __restrict__ atoms,
    const float* __restrict__ bonds,
    const int*   __restrict__ edges,
    const float* __restrict__ W_inner,
    const float* __restrict__ b_inner,
    const float* __restrict__ b_self,
    const unsigned short* __restrict__ wsb,
    float* __restrict__ out)
{
    // 24576 + 31744 + 4096 + 1024 = 61440 B static LDS (r2 structure, frag-order W).
    __shared__ __align__(16) unsigned short s_w[NC * KTOT];  // fragment-ordered W, 24.6 KB
    __shared__ __align__(16) float s_atoms[NM * NFA];        // [row][62] fp32, 31.7 KB
    __shared__ __align__(16) float s_bsf[4][32][8];          // per row: [bs2..bs5, bs0,bs1, -, -]
    __shared__ float s_sf[4][64];                            // sparse-path summed-atom features

    const int tid  = threadIdx.x;
    const int w    = tid >> 6;
    const int lane = tid & 63;
    const int b    = blockIdx.x;
    const int m0   = w * 32;      // this wave owns rows m0..m0+31

    const float* atoms_b = atoms + (size_t)b * (NM * NFA);
    const float* bonds_b = bonds + (size_t)b * (NM * ND * NFB);
    const int*   edges_b = edges + (size_t)b * (NM * ND);
    float*       out_b   = out   + (size_t)b * (NM * NC);

    // ---- async stage W (24 chunks) + atoms (31 chunks) into LDS, 1 KiB chunks ----
    {
        const char* gw = (const char*)wsb;
        const char* ga = (const char*)atoms_b;
        char* lw = (char*)s_w;
        char* la = (char*)s_atoms;
        for (int ch = w; ch < 24; ch += 4)          // wave-uniform guard, no lane masking
            glds16(gw + ch * 1024 + lane * 16, lw + ch * 1024);
        for (int ch = w; ch < 31; ch += 4)
            glds16(ga + ch * 1024 + lane * 16, la + ch * 1024);
    }

    // ---- edges + degree (lanes 0..31, one row each) — overlaps staging ----
    int E0 = -1, E1 = -1, E2 = -1, E3 = -1, E4 = -1, deg = ND;
    if (lane < 32) {
        const int* e = edges_b + (m0 + lane) * ND;
        E0 = e[0]; E1 = e[1]; E2 = e[2]; E3 = e[3]; E4 = e[4];
        deg = (E0 >= 0) + (E1 >= 0) + (E2 >= 0) + (E3 >= 0) + (E4 >= 0);
    }
    unsigned long long smask = __ballot((lane < 32) && (deg < ND));

    // ---- bond sums from global: 2 lanes per row, combine via shfl_xor ----
    {
        const int rb = lane >> 1, half = lane & 1;
        const float* bp = bonds_b + (m0 + rb) * (ND * NFB);
        float sb[NFB] = {0.f, 0.f, 0.f, 0.f, 0.f, 0.f};
        if (half == 0) {
            #pragma unroll
            for (int p = 0; p < 8; ++p) {
                float2 v = *(const float2*)&bp[2 * p];
                sb[(2 * p) % NFB]     += v.x;
                sb[(2 * p + 1) % NFB] += v.y;
            }
        } else {
            #pragma unroll
            for (int p = 8; p < 15; ++p) {
                float2 v = *(const float2*)&bp[2 * p];
                sb[(2 * p) % NFB]     += v.x;
                sb[(2 * p + 1) % NFB] += v.y;
            }
        }
        #pragma unroll
        for (int j = 0; j < NFB; ++j) sb[j] += __shfl_xor(sb[j], 1);
        if (half == 0) {
            *(float4*)&s_bsf[w][rb][0] = make_float4(sb[2], sb[3], sb[4], sb[5]);
            *(float2*)&s_bsf[w][rb][4] = make_float2(sb[0], sb[1]);
        }
    }

    __syncthreads();   // drains global_load_lds (vmcnt) + LDS writes; one barrier total

    // ---- build A-fragments (vxi) from LDS atoms, MFMA A-layout ----
    const int col = lane & 15, quad = lane >> 4;
    const int lr0 = col, lr1 = 16 + col;          // wave-local rows
    const float* p0 = s_atoms + (m0 + lr0) * NFA;
    const float* p1 = s_atoms + (m0 + lr1) * NFA;

    bf16x8 a00 = load8(p0 + quad * 8);
    bf16x8 a10 = load8(p1 + quad * 8);
    bf16x8 a01, a11;
    if (quad < 3) {
        a01 = load8(p0 + 32 + quad * 8);
        a11 = load8(p1 + 32 + quad * 8);
    } else {
        a01 = load6bs(p0 + 56, &s_bsf[w][lr0][4]);
        a11 = load6bs(p1 + 56, &s_bsf[w][lr1][4]);
    }
    bf16x8 a02, a12;
    #pragma unroll
    for (int j = 0; j < 8; ++j) { a02[j] = (__bf16)0.f; a12[j] = (__bf16)0.f; }
    if (quad == 0) {
        float4 q0 = *(const float4*)&s_bsf[w][lr0][0];
        float4 q1 = *(const float4*)&s_bsf[w][lr1][0];
        a02[0] = (__bf16)q0.x; a02[1] = (__bf16)q0.y; a02[2] = (__bf16)q0.z; a02[3] = (__bf16)q0.w;
        a12[0] = (__bf16)q1.x; a12[1] = (__bf16)q1.y; a12[2] = (__bf16)q1.z; a12[3] = (__bf16)q1.w;
    }

    // ---- MFMA: W fragments from LDS, linear base + lane*16 (conflict-free) ----
    floatx4 acc[16];
    #pragma unroll
    for (int t = 0; t < 16; ++t) { floatx4 z; z[0] = z[1] = z[2] = z[3] = 0.f; acc[t] = z; }

    const unsigned short* wl = s_w + lane * 8;   // 8 shorts = 16 B per fragment
    #pragma unroll
    for (int ct = 0; ct < 8; ++ct) {
        bf16x8 wf0 = *(const bf16x8*)(wl + (ct * 3 + 0) * 512);  // k  0..31, col ct*16+col
        bf16x8 wf1 = *(const bf16x8*)(wl + (ct * 3 + 1) * 512);  // k 32..63
        bf16x8 wf2 = *(const bf16x8*)(wl + (ct * 3 + 2) * 512);  // k 64..95 (rows>=68 zero)
        acc[ct]     = __builtin_amdgcn_mfma_f32_16x16x32_bf16(a00, wf0, acc[ct],     0, 0, 0);
        acc[8 + ct] = __builtin_amdgcn_mfma_f32_16x16x32_bf16(a10, wf0, acc[8 + ct], 0, 0, 0);
        acc[ct]     = __builtin_amdgcn_mfma_f32_16x16x32_bf16(a01, wf1, acc[ct],     0, 0, 0);
        acc[8 + ct] = __builtin_amdgcn_mfma_f32_16x16x32_bf16(a11, wf1, acc[8 + ct], 0, 0, 0);
        acc[ct]     = __builtin_amdgcn_mfma_f32_16x16x32_bf16(a02, wf2, acc[ct],     0, 0, 0);
        acc[8 + ct] = __builtin_amdgcn_mfma_f32_16x16x32_bf16(a12, wf2, acc[8 + ct], 0, 0, 0);
    }

    // ---- epilogue: bias + relu, coalesced dword stores (full 64B lines) ----
    #pragma unroll
    for (int ct = 0; ct < 8; ++ct) {
        const float bias = b_self[ct * 16 + col];
        #pragma unroll
        for (int rr = 0; rr < 4; ++rr) {
            const int row0 = m0 + quad * 4 + rr;
            out_b[row0 * NC + ct * 16 + col]        = fmaxf(acc[ct][rr]     + bias, 0.f);
            out_b[(row0 + 16) * NC + ct * 16 + col] = fmaxf(acc[8 + ct][rr] + bias, 0.f);
        }
    }

    // ---- sparse path: rows with deg<5 (~1.2/wave); neighbor gathers from LDS
    //      (all 128 rows staged; post-barrier so every wave's chunks landed) ----
    while (smask) {
        const int ml = __ffsll(smask) - 1;
        smask &= smask - 1;
        const int m  = m0 + ml;
        const int d  = __shfl(deg, ml);
        const int e0 = __shfl(E0, ml), e1 = __shfl(E1, ml), e2 = __shfl(E2, ml),
                  e3 = __shfl(E3, ml), e4 = __shfl(E4, ml);

        if (lane < NFA) {   // conflict-free LDS gathers (62 consecutive dwords per row)
            float sv = 0.f;
            if (e0 >= 0) sv += s_atoms[e0 * NFA + lane];
            if (e1 >= 0) sv += s_atoms[e1 * NFA + lane];
            if (e2 >= 0) sv += s_atoms[e2 * NFA + lane];
            if (e3 >= 0) sv += s_atoms[e3 * NFA + lane];
            if (e4 >= 0) sv += s_atoms[e4 * NFA + lane];
            s_sf[w][lane] = sv;
        }
        __builtin_amdgcn_wave_barrier();

        const int c0 = 2 * lane;
        float2 bi = *(const float2*)&b_inner[d * NC + c0];
        float acc0 = bi.x, acc1 = bi.y;
        const float* Wd = W_inner + (size_t)d * (NFAN * NC);
        #pragma unroll
        for (int f = 0; f < NFA; ++f) {
            const float sfv = s_sf[w][f];
            float2 wv = *(const float2*)&Wd[f * NC + c0];
            acc0 += sfv * wv.x; acc1 += sfv * wv.y;
        }
        {
            const float* bb = &s_bsf[w][ml][0];
            const float fv[6] = {bb[4], bb[5], bb[0], bb[1], bb[2], bb[3]}; // bs0..bs5
            #pragma unroll
            for (int j = 0; j < NFB; ++j) {
                float2 wv = *(const float2*)&Wd[(NFA + j) * NC + c0];
                acc0 += fv[j] * wv.x; acc1 += fv[j] * wv.y;
            }
        }
        float2 cur = *(float2*)&out_b[m * NC + c0];
        cur.x += fmaxf(acc0, 0.f);
        cur.y += fmaxf(acc1, 0.f);
        *(float2*)&out_b[m * NC + c0] = cur;
        __builtin_amdgcn_wave_barrier();
    }
}

extern "C" void kernel_launch(void* const* d_in, const int* in_sizes, int n_in,
                              void* d_out, int out_size, void* d_ws, size_t ws_size,
                              hipStream_t stream) {
    const float* atoms   = (const float*)d_in[0];
    const float* bonds   = (const float*)d_in[1];
    const int*   edges   = (const int*)d_in[2];
    const float* W_inner = (const float*)d_in[3];
    const float* b_inner = (const float*)d_in[4];
    const float* W_self  = (const float*)d_in[5];
    const float* b_self  = (const float*)d_in[6];
    float* out = (float*)d_out;
    unsigned short* wsb = (unsigned short*)d_ws;   // 128*96*2 = 24576 B

    prep_w<<<(NC * KTOT) / 256, 256, 0, stream>>>(W_self, wsb);
    tga_wave<<<NB, 256, 0, stream>>>(atoms, bonds, edges, W_inner, b_inner,
                                     b_self, wsb, out);
}